// Round 12
// baseline (285.134 us; speedup 1.0000x reference)
//
#include <hip/hip_runtime.h>
#include <hip/hip_bf16.h>

typedef __bf16 bf16_t;
typedef bf16_t bf16x8 __attribute__((ext_vector_type(8)));
typedef bf16_t bf16x4 __attribute__((ext_vector_type(4)));
typedef float f32x4 __attribute__((ext_vector_type(4)));

#define SCALE 0.17677669529663687f  // 32^-0.5

// keep a loaded value live / pinned at this program point (defeats load sinking)
#define PIN(x) asm volatile("" : "+v"(x))

// Swizzled element offset within a 32x192 bf16 chunk image (row stride 384 B).
__device__ __forceinline__ int swz_elem(int r, int c) {
    int g = c >> 3;
    return r * 192 + ((g >> 3) << 6) + (((g & 7) ^ (r & 7)) << 3) + (c & 7);
}

// async global->LDS: 16B per lane, linear dest (lane-order = image order)
__device__ __forceinline__ void stage_chunk(bf16_t* dst, const bf16_t* src, int tid) {
#pragma unroll
    for (int it = 0; it < 3; ++it) {
        int off = (it * 256 + tid) * 8;   // 3*256*8 = 6144 elems = 12288 B
        __builtin_amdgcn_global_load_lds(
            (const __attribute__((address_space(1))) unsigned int*)(src + off),
            (__attribute__((address_space(3))) unsigned int*)(dst + off),
            16, 0, 0);
    }
}

// ======================= prep: weights -> swizzled bf16 chunk images ========
__global__ void prep_weights(const float* __restrict__ w_qkv, const float* __restrict__ w_out,
                             bf16_t* __restrict__ wqkvS, bf16_t* __restrict__ woutS) {
    int i = blockIdx.x * 256 + threadIdx.x;
    if (i < 576 * 192) {
        int o = i / 192, k = i % 192;
        float v = w_qkv[k * 576 + o];
        if (o < 192) v *= SCALE;
        wqkvS[(o >> 5) * 6144 + swz_elem(o & 31, k)] = (bf16_t)v;
    }
    if (i < 192 * 192) {
        int o = i / 192, k = i % 192;
        woutS[(o >> 5) * 6144 + swz_elem(o & 31, k)] = (bf16_t)w_out[k * 192 + o];
    }
}

// ======================= prep: bias/mask -> bf16, lane-permuted =============
// Region = (wh, t) for bias (wh = ww*6+h, 6696 regions) or (bw, t) for mask
// (8928 regions). Region holds 2560 bf16 = [it 0..4][lane 0..63][8 elems];
// element u = it*8+e encodes (nt = u>>2, j = u&3): value =
// src[row = t*16 + (lane&15)][m = nt*16 + (lane>>4)*4 + j], u>=36 -> 0 pad.
// One thread per (region, lane); writes are 1KB-contiguous per wave.
__global__ __launch_bounds__(256)
void prep_bm(const float* __restrict__ bias, const float* __restrict__ mask,
             bf16_t* __restrict__ biasP, bf16_t* __restrict__ maskP)
{
    int gid = blockIdx.x * 256 + threadIdx.x;
    const int NB = 6696 * 64;
    const int NM = 8928 * 64;
    bool isMask = gid >= NB;
    if (isMask) gid -= NB;
    if (isMask && gid >= NM) return;
    const int lane = gid & 63;
    const int region = gid >> 6;
    const int lrow = lane & 15, lgrp = lane >> 4;
    const int t = region % 9, rg = region / 9;
    const float* src = (isMask ? mask : bias) + ((size_t)rg * 144 + t * 16 + lrow) * 144 + lgrp * 4;
    bf16_t* dst = (isMask ? maskP : biasP) + (size_t)region * 2560 + lane * 8;
#pragma unroll
    for (int it = 0; it < 5; ++it) {
        f32x4 v0 = *(const f32x4*)(src + it * 32);
        bf16x8 o;
        o[0] = (bf16_t)v0[0]; o[1] = (bf16_t)v0[1]; o[2] = (bf16_t)v0[2]; o[3] = (bf16_t)v0[3];
        if (it < 4) {
            f32x4 v1 = *(const f32x4*)(src + it * 32 + 16);
            o[4] = (bf16_t)v1[0]; o[5] = (bf16_t)v1[1]; o[6] = (bf16_t)v1[2]; o[7] = (bf16_t)v1[3];
        } else {
            o[4] = o[5] = o[6] = o[7] = (bf16_t)0.f;
        }
        *(bf16x8*)(dst + it * 512) = o;
    }
}

// ======================= kernel 1: QKV projection GEMM ======================
__global__ __launch_bounds__(256, 4)
void qkv_gemm(const float* __restrict__ x, const float* __restrict__ b_qkv,
              const bf16_t* __restrict__ wqkvS,
              bf16_t* __restrict__ Qg, bf16_t* __restrict__ Kg, bf16_t* __restrict__ Vt)
{
    __shared__ __align__(16) bf16_t Wb[2][6144];      // 24576 B
    __shared__ __align__(16) bf16_t T[4][1280];       // 10240 B (wave-private)
    const int tid  = threadIdx.x;
    const int lane = tid & 63;
    const int wave = tid >> 6;
    const int lrow = lane & 15;
    const int lgrp = lane >> 4;
    const int r0   = blockIdx.x * 128 + wave * 32;

    stage_chunk(&Wb[0][0], wqkvS, tid);   // chunk 0

    bf16x8 af[2][6];
#pragma unroll
    for (int tt = 0; tt < 2; ++tt)
#pragma unroll
        for (int ks = 0; ks < 6; ++ks) {
            const float* px = x + (size_t)(r0 + tt * 16 + lrow) * 192 + ks * 32 + lgrp * 8;
            f32x4 lo = *(const f32x4*)px;
            f32x4 hi = *(const f32x4*)(px + 4);
            bf16x8 v;
            v[0] = (bf16_t)lo[0]; v[1] = (bf16_t)lo[1]; v[2] = (bf16_t)lo[2]; v[3] = (bf16_t)lo[3];
            v[4] = (bf16_t)hi[0]; v[5] = (bf16_t)hi[1]; v[6] = (bf16_t)hi[2]; v[7] = (bf16_t)hi[3];
            af[tt][ks] = v;
        }
    __syncthreads();   // chunk 0 resident

    bf16_t* tl = &T[wave][0];

    for (int hc = 0; hc < 18; ++hc) {
        if (hc < 17) stage_chunk(&Wb[(hc + 1) & 1][0], wqkvS + (hc + 1) * 6144, tid);
        const bf16_t* wb = &Wb[hc & 1][0];

        f32x4 a[2][2];
        a[0][0] = f32x4{0.f,0.f,0.f,0.f}; a[0][1] = f32x4{0.f,0.f,0.f,0.f};
        a[1][0] = f32x4{0.f,0.f,0.f,0.f}; a[1][1] = f32x4{0.f,0.f,0.f,0.f};
#pragma unroll
        for (int ks = 0; ks < 6; ++ks) {
            bf16x8 wf0 = *(const bf16x8*)&wb[swz_elem(lrow,      ks * 32 + lgrp * 8)];
            bf16x8 wf1 = *(const bf16x8*)&wb[swz_elem(16 + lrow, ks * 32 + lgrp * 8)];
#pragma unroll
            for (int tt = 0; tt < 2; ++tt) {
                a[tt][0] = __builtin_amdgcn_mfma_f32_16x16x32_bf16(af[tt][ks], wf0, a[tt][0], 0, 0, 0);
                a[tt][1] = __builtin_amdgcn_mfma_f32_16x16x32_bf16(af[tt][ks], wf1, a[tt][1], 0, 0, 0);
            }
        }
        __syncthreads();   // chunk hc reads done; stage hc+1 drained

        float b0 = b_qkv[hc * 32 + lrow], b1 = b_qkv[hc * 32 + 16 + lrow];
        if (hc < 6) { b0 *= SCALE; b1 *= SCALE; }

        if (hc < 12) {
            const int h = (hc < 6) ? hc : hc - 6;
            bf16_t* dst = (hc < 6) ? Qg : Kg;
#pragma unroll
            for (int tt = 0; tt < 2; ++tt) {
#pragma unroll
                for (int j = 0; j < 4; ++j) {
                    tl[tt * 640 + (lgrp * 4 + j) * 40 + lrow]      = (bf16_t)(a[tt][0][j] + b0);
                    tl[tt * 640 + (lgrp * 4 + j) * 40 + 16 + lrow] = (bf16_t)(a[tt][1][j] + b1);
                }
                bf16x8 val = *(const bf16x8*)&tl[tt * 640 + lrow * 40 + lgrp * 8];
                int tk = r0 + tt * 16 + lrow, bw = tk / 144, n = tk % 144;
                *(bf16x8*)&dst[((size_t)(bw * 6 + h) * 144 + n) * 32 + lgrp * 8] = val;
            }
        } else {
            const int hv = hc - 12;
#pragma unroll
            for (int tt = 0; tt < 2; ++tt)
#pragma unroll
                for (int j = 0; j < 4; ++j) {
                    tl[(lrow) * 40      + tt * 16 + lgrp * 4 + j] = (bf16_t)(a[tt][0][j] + b0);
                    tl[(16 + lrow) * 40 + tt * 16 + lgrp * 4 + j] = (bf16_t)(a[tt][1][j] + b1);
                }
#pragma unroll
            for (int it = 0; it < 2; ++it) {
                int slot = it * 64 + lane;          // 128 slots = 32 d x 4 col-groups
                int d = slot >> 2, c = slot & 3;    // c*8 = 8-token group (8 | 144)
                int tk = r0 + c * 8, bw = tk / 144, n = tk % 144;
                bf16x8 val = *(const bf16x8*)&tl[d * 40 + c * 8];
                *(bf16x8*)&Vt[((size_t)(bw * 6 + hv) * 32 + d) * 160 + n] = val;
            }
        }
    }
}

// ======================= kernel 2: attention v8 (bf16 permuted bias/mask) ===
// grid 1488 x 256 thr (4 waves). wave-task = (bw, h): K/V register-resident,
// 9 q-tiles; Q + permuted-bf16 bias/mask prefetched one tile ahead.
__global__ __launch_bounds__(256, 2)
void earth_attn_v8(const bf16_t* __restrict__ Qg, const bf16_t* __restrict__ Kg,
                   const bf16_t* __restrict__ Vt,
                   const bf16_t* __restrict__ maskP, const bf16_t* __restrict__ biasP,
                   bf16_t* __restrict__ Og)
{
    __shared__ bf16_t P[4][16 * 168];   // 21504 B, wave-private tiles
    const int tid  = threadIdx.x;
    const int lane = tid & 63;
    const int wave = tid >> 6;
    const int lrow = lane & 15;
    const int lgrp = lane >> 4;

    // bijective XCD swizzle: 1488 = 8 * 186 (contiguous chunk per XCD)
    const int orig = blockIdx.x;
    const int blk  = (orig & 7) * 186 + (orig >> 3);

    // ww-major task order (bias slice L2-hot within an XCD chunk)
    const int wid = blk * 4 + wave;          // 0..5951
    const int ww  = wid / 48;                // 0..123
    const int r1  = wid % 48;
    const int b   = r1 / 6;                  // 0..7
    const int h   = r1 % 6;
    const int bw  = b * 124 + ww;

    const size_t kbase = ((size_t)(bw * 6 + h) * 144) * 32;
    const size_t vbase = ((size_t)(bw * 6 + h) * 32) * 160;

    // ---- K fragments: loaded ONCE, register-resident for all 9 q-tiles -----
    bf16x8 ka[9];
#pragma unroll
    for (int nt = 0; nt < 9; ++nt)
        ka[nt] = *(const bf16x8*)&Kg[kbase + (size_t)(nt * 16 + lrow) * 32 + lgrp * 8];

    // ---- V fragments: loaded ONCE, register-resident ------------------------
    bf16x8 va0[5], va1[5];
#pragma unroll
    for (int ks = 0; ks < 5; ++ks) {
        va0[ks] = *(const bf16x8*)&Vt[vbase + (size_t)lrow * 160 + ks * 32 + lgrp * 8];
        va1[ks] = *(const bf16x8*)&Vt[vbase + (size_t)(16 + lrow) * 160 + ks * 32 + lgrp * 8];
    }

    const bf16_t* bpB = biasP + (size_t)(ww * 6 + h) * 9 * 2560 + lane * 8;
    const bf16_t* mpB = maskP + (size_t)bw * 9 * 2560 + lane * 8;
    bf16_t* pb = &P[wave][0];
    bf16_t* ogp = Og + ((size_t)bw * 144) * 192 + h * 32 + lgrp * 8;

    // ---- preload tile 0: Q + permuted bias/mask ------------------------------
    bf16x8 qa = *(const bf16x8*)&Qg[kbase + (size_t)lrow * 32 + lgrp * 8];
    bf16x8 bvv[5], mvv[5];
#pragma unroll
    for (int it = 0; it < 5; ++it) {
        bvv[it] = *(const bf16x8*)(bpB + it * 512);
        mvv[it] = *(const bf16x8*)(mpB + it * 512);
    }

#pragma unroll 1
    for (int t = 0; t < 9; ++t) {
        // ---- consume prefetched bias/mask into S C-init ----------------------
        f32x4 s[9];
#pragma unroll
        for (int nt = 0; nt < 9; ++nt)
#pragma unroll
            for (int j = 0; j < 4; ++j) {
                const int u = nt * 4 + j;
                s[nt][j] = (float)bvv[u >> 3][u & 7] + (float)mvv[u >> 3][u & 7];
            }

        // ---- issue NEXT tile's Q + bias/mask (hidden under MFMA/softmax/PV) --
        const int tn = (t < 8) ? t + 1 : 8;
        bf16x8 qa_n = *(const bf16x8*)&Qg[kbase + (size_t)(tn * 16 + lrow) * 32 + lgrp * 8];
        PIN(qa_n);
#pragma unroll
        for (int it = 0; it < 5; ++it) {
            bvv[it] = *(const bf16x8*)(bpB + (size_t)tn * 2560 + it * 512);
            mvv[it] = *(const bf16x8*)(mpB + (size_t)tn * 2560 + it * 512);
        }
#pragma unroll
        for (int it = 0; it < 5; ++it) { PIN(bvv[it]); PIN(mvv[it]); }

        // ---- S^T = K Q^T + C-init (all register operands) --------------------
#pragma unroll
        for (int nt = 0; nt < 9; ++nt)
            s[nt] = __builtin_amdgcn_mfma_f32_16x16x32_bf16(ka[nt], qa, s[nt], 0, 0, 0);

        // ---- softmax (lane owns q-row t*16+lrow; m spread over lgrp) ---------
        float mx = -1e30f;
#pragma unroll
        for (int nt = 0; nt < 9; ++nt)
#pragma unroll
            for (int j = 0; j < 4; ++j) mx = fmaxf(mx, s[nt][j]);
        mx = fmaxf(mx, __shfl_xor(mx, 16, 64));
        mx = fmaxf(mx, __shfl_xor(mx, 32, 64));
        float sum = 0.f;
#pragma unroll
        for (int nt = 0; nt < 9; ++nt)
#pragma unroll
            for (int j = 0; j < 4; ++j) { float e = __expf(s[nt][j] - mx); s[nt][j] = e; sum += e; }
        sum += __shfl_xor(sum, 16, 64);
        sum += __shfl_xor(sum, 32, 64);
        const float rinv = 1.0f / sum;

        // ---- P -> wave-private LDS, zero tail cols [144,160) -----------------
#pragma unroll
        for (int nt = 0; nt < 9; ++nt) {
            bf16x4 pw;
#pragma unroll
            for (int j = 0; j < 4; ++j) pw[j] = (bf16_t)(s[nt][j] * rinv);
            *(bf16x4*)&pb[lrow * 168 + nt * 16 + lgrp * 4] = pw;
        }
        {
            uint2 z2 = make_uint2(0u, 0u);
            *(uint2*)&pb[lrow * 168 + 144 + lgrp * 4] = z2;
        }

        // ---- P fragments, PV MFMAs -------------------------------------------
        bf16x8 pa[5];
#pragma unroll
        for (int ks = 0; ks < 5; ++ks)
            pa[ks] = *(const bf16x8*)&pb[lrow * 168 + ks * 32 + lgrp * 8];
#pragma unroll
        for (int ks = 0; ks < 5; ++ks) PIN(pa[ks]);

        f32x4 o0{0.f, 0.f, 0.f, 0.f}, o1{0.f, 0.f, 0.f, 0.f};
#pragma unroll
        for (int ks = 0; ks < 5; ++ks) {
            o0 = __builtin_amdgcn_mfma_f32_16x16x32_bf16(pa[ks], va0[ks], o0, 0, 0, 0);
            o1 = __builtin_amdgcn_mfma_f32_16x16x32_bf16(pa[ks], va1[ks], o1, 0, 0, 0);
        }

        // ---- O transpose via pb reuse (wave-private, in-order), store --------
#pragma unroll
        for (int j = 0; j < 4; ++j) {
            pb[(lgrp * 4 + j) * 168 + lrow]      = (bf16_t)o0[j];
            pb[(lgrp * 4 + j) * 168 + 16 + lrow] = (bf16_t)o1[j];
        }
        bf16x8 ov = *(const bf16x8*)&pb[lrow * 168 + lgrp * 8];
        *(bf16x8*)(ogp + (size_t)(t * 16 + lrow) * 192) = ov;

        qa = qa_n;
    }
}

// ======================= fallback attention (fp32 bias/mask, R11) ===========
__global__ __launch_bounds__(256, 2)
void earth_attn_v7(const bf16_t* __restrict__ Qg, const bf16_t* __restrict__ Kg,
                   const bf16_t* __restrict__ Vt,
                   const float* __restrict__ mask, const float* __restrict__ bias,
                   bf16_t* __restrict__ Og)
{
    __shared__ bf16_t P[4][16 * 168];
    const int tid  = threadIdx.x;
    const int lane = tid & 63;
    const int wave = tid >> 6;
    const int lrow = lane & 15;
    const int lgrp = lane >> 4;
    const int orig = blockIdx.x;
    const int blk  = (orig & 7) * 186 + (orig >> 3);
    const int wid = blk * 4 + wave;
    const int ww  = wid / 48;
    const int r1  = wid % 48;
    const int b   = r1 / 6;
    const int h   = r1 % 6;
    const int bw  = b * 124 + ww;
    const size_t kbase = ((size_t)(bw * 6 + h) * 144) * 32;
    const size_t vbase = ((size_t)(bw * 6 + h) * 32) * 160;

    bf16x8 ka[9];
#pragma unroll
    for (int nt = 0; nt < 9; ++nt)
        ka[nt] = *(const bf16x8*)&Kg[kbase + (size_t)(nt * 16 + lrow) * 32 + lgrp * 8];
    bf16x8 va0[5], va1[5];
#pragma unroll
    for (int ks = 0; ks < 5; ++ks) {
        va0[ks] = *(const bf16x8*)&Vt[vbase + (size_t)lrow * 160 + ks * 32 + lgrp * 8];
        va1[ks] = *(const bf16x8*)&Vt[vbase + (size_t)(16 + lrow) * 160 + ks * 32 + lgrp * 8];
    }
    const float* bp_base = bias + (size_t)(ww * 6 + h) * 144 * 144;
    const float* mp_base = mask + (size_t)bw * 144 * 144;
    bf16_t* pb = &P[wave][0];
    bf16_t* ogp = Og + ((size_t)bw * 144) * 192 + h * 32 + lgrp * 8;
    bf16x8 qa = *(const bf16x8*)&Qg[kbase + (size_t)lrow * 32 + lgrp * 8];
    f32x4 bv[9], mv[9];
    {
        const float* bp = bp_base + (size_t)lrow * 144;
        const float* mp = mp_base + (size_t)lrow * 144;
#pragma unroll
        for (int nt = 0; nt < 9; ++nt) {
            bv[nt] = *(const f32x4*)(bp + nt * 16 + lgrp * 4);
            mv[nt] = *(const f32x4*)(mp + nt * 16 + lgrp * 4);
        }
    }
#pragma unroll 1
    for (int t = 0; t < 9; ++t) {
        f32x4 s[9];
#pragma unroll
        for (int nt = 0; nt < 9; ++nt) s[nt] = bv[nt] + mv[nt];
        const int tn = (t < 8) ? t + 1 : 8;
        bf16x8 qa_n = *(const bf16x8*)&Qg[kbase + (size_t)(tn * 16 + lrow) * 32 + lgrp * 8];
        PIN(qa_n);
        {
            const float* bp = bp_base + (size_t)(tn * 16 + lrow) * 144;
            const float* mp = mp_base + (size_t)(tn * 16 + lrow) * 144;
#pragma unroll
            for (int nt = 0; nt < 9; ++nt) {
                bv[nt] = *(const f32x4*)(bp + nt * 16 + lgrp * 4);
                mv[nt] = *(const f32x4*)(mp + nt * 16 + lgrp * 4);
            }
#pragma unroll
            for (int nt = 0; nt < 9; ++nt) { PIN(bv[nt]); PIN(mv[nt]); }
        }
#pragma unroll
        for (int nt = 0; nt < 9; ++nt)
            s[nt] = __builtin_amdgcn_mfma_f32_16x16x32_bf16(ka[nt], qa, s[nt], 0, 0, 0);
        float mx = -1e30f;
#pragma unroll
        for (int nt = 0; nt < 9; ++nt)
#pragma unroll
            for (int j = 0; j < 4; ++j) mx = fmaxf(mx, s[nt][j]);
        mx = fmaxf(mx, __shfl_xor(mx, 16, 64));
        mx = fmaxf(mx, __shfl_xor(mx, 32, 64));
        float sum = 0.f;
#pragma unroll
        for (int nt = 0; nt < 9; ++nt)
#pragma unroll
            for (int j = 0; j < 4; ++j) { float e = __expf(s[nt][j] - mx); s[nt][j] = e; sum += e; }
        sum += __shfl_xor(sum, 16, 64);
        sum += __shfl_xor(sum, 32, 64);
        const float rinv = 1.0f / sum;
#pragma unroll
        for (int nt = 0; nt < 9; ++nt) {
            bf16x4 pw;
#pragma unroll
            for (int j = 0; j < 4; ++j) pw[j] = (bf16_t)(s[nt][j] * rinv);
            *(bf16x4*)&pb[lrow * 168 + nt * 16 + lgrp * 4] = pw;
        }
        {
            uint2 z2 = make_uint2(0u, 0u);
            *(uint2*)&pb[lrow * 168 + 144 + lgrp * 4] = z2;
        }
        bf16x8 pa[5];
#pragma unroll
        for (int ks = 0; ks < 5; ++ks)
            pa[ks] = *(const bf16x8*)&pb[lrow * 168 + ks * 32 + lgrp * 8];
#pragma unroll
        for (int ks = 0; ks < 5; ++ks) PIN(pa[ks]);
        f32x4 o0{0.f, 0.f, 0.f, 0.f}, o1{0.f, 0.f, 0.f, 0.f};
#pragma unroll
        for (int ks = 0; ks < 5; ++ks) {
            o0 = __builtin_amdgcn_mfma_f32_16x16x32_bf16(pa[ks], va0[ks], o0, 0, 0, 0);
            o1 = __builtin_amdgcn_mfma_f32_16x16x32_bf16(pa[ks], va1[ks], o1, 0, 0, 0);
        }
#pragma unroll
        for (int j = 0; j < 4; ++j) {
            pb[(lgrp * 4 + j) * 168 + lrow]      = (bf16_t)o0[j];
            pb[(lgrp * 4 + j) * 168 + 16 + lrow] = (bf16_t)o1[j];
        }
        bf16x8 ov = *(const bf16x8*)&pb[lrow * 168 + lgrp * 8];
        *(bf16x8*)(ogp + (size_t)(t * 16 + lrow) * 192) = ov;
        qa = qa_n;
    }
}

// ======================= kernel 3: out-projection GEMM ======================
__global__ __launch_bounds__(256, 4)
void out_proj(const bf16_t* __restrict__ Og, const bf16_t* __restrict__ woutS,
              const float* __restrict__ b_out, float* __restrict__ out)
{
    __shared__ __align__(16) bf16_t Wb[2][6144];
    const int tid  = threadIdx.x;
    const int lane = tid & 63;
    const int wave = tid >> 6;
    const int lrow = lane & 15;
    const int lgrp = lane >> 4;
    const size_t row0 = (size_t)blockIdx.x * 64 + wave * 16;

    stage_chunk(&Wb[0][0], woutS, tid);

    bf16x8 af[6];
#pragma unroll
    for (int ks = 0; ks < 6; ++ks)
        af[ks] = *(const bf16x8*)(Og + (row0 + lrow) * 192 + ks * 32 + lgrp * 8);
    __syncthreads();

#pragma unroll
    for (int c = 0; c < 6; ++c) {
        if (c < 5) stage_chunk(&Wb[(c + 1) & 1][0], woutS + (c + 1) * 6144, tid);
        const bf16_t* wb = &Wb[c & 1][0];
        float b0 = b_out[c * 32 + lrow], b1 = b_out[c * 32 + 16 + lrow];
        f32x4 a0{b0, b0, b0, b0}, a1{b1, b1, b1, b1};
#pragma unroll
        for (int ks = 0; ks < 6; ++ks) {
            bf16x8 wf0 = *(const bf16x8*)&wb[swz_elem(lrow,      ks * 32 + lgrp * 8)];
            bf16x8 wf1 = *(const bf16x8*)&wb[swz_elem(16 + lrow, ks * 32 + lgrp * 8)];
            a0 = __builtin_amdgcn_mfma_f32_16x16x32_bf16(af[ks], wf0, a0, 0, 0, 0);
            a1 = __builtin_amdgcn_mfma_f32_16x16x32_bf16(af[ks], wf1, a1, 0, 0, 0);
        }
        __syncthreads();
#pragma unroll
        for (int j = 0; j < 4; ++j) {
            out[(row0 + lgrp * 4 + j) * 192 + c * 32 + lrow]      = a0[j];
            out[(row0 + lgrp * 4 + j) * 192 + c * 32 + 16 + lrow] = a1[j];
        }
    }
}

// ======================= launch =============================================
extern "C" void kernel_launch(void* const* d_in, const int* in_sizes, int n_in,
                              void* d_out, int out_size, void* d_ws, size_t ws_size,
                              hipStream_t stream) {
    const float* x     = (const float*)d_in[0];
    const float* mask  = (const float*)d_in[1];
    const float* w_qkv = (const float*)d_in[2];
    const float* b_qkv = (const float*)d_in[3];
    const float* bias  = (const float*)d_in[4];
    const float* w_out = (const float*)d_in[5];
    const float* b_out = (const float*)d_in[6];

    bf16_t* wqkvS = (bf16_t*)d_ws;                     //    110,592 elems
    bf16_t* woutS = wqkvS + 576 * 192;                 //     36,864
    bf16_t* Qg    = woutS + 192 * 192;                 // 27,426,816
    bf16_t* Kg    = Qg + (size_t)992 * 6 * 144 * 32;   // 27,426,816
    bf16_t* Vt    = Kg + (size_t)992 * 6 * 144 * 32;   // 30,474,240
    bf16_t* Og    = Vt + (size_t)992 * 6 * 32 * 160;   // 27,426,816
    bf16_t* biasP = Og + (size_t)992 * 144 * 192;      // 17,141,760
    bf16_t* maskP = biasP + (size_t)6696 * 2560;       // 22,855,680

    const size_t need_v8 = ((size_t)112902144 + 17141760 + 22855680) * 2;   // ~306 MB

    prep_weights<<<dim3(432), dim3(256), 0, stream>>>(w_qkv, w_out, wqkvS, woutS);
    qkv_gemm<<<dim3(1116), dim3(256), 0, stream>>>(x, b_qkv, wqkvS, Qg, Kg, Vt);

    if (ws_size >= need_v8) {
        prep_bm<<<dim3(3906), dim3(256), 0, stream>>>(bias, mask, biasP, maskP);
        earth_attn_v8<<<dim3(1488), dim3(256), 0, stream>>>(Qg, Kg, Vt, maskP, biasP, Og);
    } else {
        earth_attn_v7<<<dim3(1488), dim3(256), 0, stream>>>(Qg, Kg, Vt, mask, bias, Og);
    }
    out_proj<<<dim3(2232), dim3(256), 0, stream>>>(Og, woutS, b_out, (float*)d_out);
}

// Round 14
// 266.136 us; speedup vs baseline: 1.0714x; 1.0714x over previous
//
#include <hip/hip_runtime.h>
#include <hip/hip_bf16.h>

typedef __bf16 bf16_t;
typedef bf16_t bf16x8 __attribute__((ext_vector_type(8)));
typedef bf16_t bf16x4 __attribute__((ext_vector_type(4)));
typedef float f32x4 __attribute__((ext_vector_type(4)));

#define SCALE 0.17677669529663687f  // 32^-0.5

// keep a loaded value live / pinned at this program point
#define PIN(x) asm volatile("" : "+v"(x))

// Swizzled element offset within a 32x192 bf16 chunk image (row stride 384 B).
__device__ __forceinline__ int swz_elem(int r, int c) {
    int g = c >> 3;
    return r * 192 + ((g >> 3) << 6) + (((g & 7) ^ (r & 7)) << 3) + (c & 7);
}

// async global->LDS: 16B per lane, linear dest (lane-order = image order)
__device__ __forceinline__ void stage_chunk(bf16_t* dst, const bf16_t* src, int tid) {
#pragma unroll
    for (int it = 0; it < 3; ++it) {
        int off = (it * 256 + tid) * 8;   // 3*256*8 = 6144 elems = 12288 B
        __builtin_amdgcn_global_load_lds(
            (const __attribute__((address_space(1))) unsigned int*)(src + off),
            (__attribute__((address_space(3))) unsigned int*)(dst + off),
            16, 0, 0);
    }
}

// stage one 1024B chunk (64 lanes x 16B), per-lane matching offsets
__device__ __forceinline__ void stage_1k(bf16_t* dst, const bf16_t* src, int lane) {
    __builtin_amdgcn_global_load_lds(
        (const __attribute__((address_space(1))) unsigned int*)(src + lane * 8),
        (__attribute__((address_space(3))) unsigned int*)(dst + lane * 8),
        16, 0, 0);
}

// ======================= prep: weights -> swizzled bf16 chunk images ========
__global__ void prep_weights(const float* __restrict__ w_qkv, const float* __restrict__ w_out,
                             bf16_t* __restrict__ wqkvS, bf16_t* __restrict__ woutS) {
    int i = blockIdx.x * 256 + threadIdx.x;
    if (i < 576 * 192) {
        int o = i / 192, k = i % 192;
        float v = w_qkv[k * 576 + o];
        if (o < 192) v *= SCALE;
        wqkvS[(o >> 5) * 6144 + swz_elem(o & 31, k)] = (bf16_t)v;
    }
    if (i < 192 * 192) {
        int o = i / 192, k = i % 192;
        woutS[(o >> 5) * 6144 + swz_elem(o & 31, k)] = (bf16_t)w_out[k * 192 + o];
    }
}

// ======================= prep: bias/mask -> bf16 permuted (coalesced) =======
// Output layout identical to R12's prep_bm (verified): region r = (rg, t) holds
// 2560 bf16 as [it 0..4][lane 0..63][e 0..7]; u=it*8+e -> (nt=u>>2, j=u&3),
// value = src[rg][t*16 + (lane&15)][nt*16 + (lane>>4)*4 + j], u>=36 -> 0.
__global__ __launch_bounds__(256, 8)
void prep_bm2(const float* __restrict__ bias, const float* __restrict__ mask,
              bf16_t* __restrict__ biasP, bf16_t* __restrict__ maskP)
{
    __shared__ bf16_t L[16 * 148];   // 4736 B
    int blk = blockIdx.x;            // [0,6696) bias, [6696,15624) mask
    bool isMask = blk >= 6696;
    int region = isMask ? blk - 6696 : blk;
    int rg = region / 9, t = region % 9;
    const float* src = (isMask ? mask : bias) + ((size_t)rg * 144 + t * 16) * 144;
    bf16_t* dst = (isMask ? maskP : biasP) + (size_t)region * 2560;
    const int tid = threadIdx.x;

    // read phase: 576 f32x4 items, coalesced
    for (int i = tid; i < 576; i += 256) {
        int row = i / 36, seg = i % 36;
        f32x4 v = *(const f32x4*)(src + row * 144 + seg * 4);
        bf16x4 o;
        o[0] = (bf16_t)v[0]; o[1] = (bf16_t)v[1]; o[2] = (bf16_t)v[2]; o[3] = (bf16_t)v[3];
        *(bf16x4*)&L[row * 148 + seg * 4] = o;
    }
    __syncthreads();

    // write phase: 320 bf16x8 items, contiguous 1KB per 64-item group
    for (int u = tid; u < 320; u += 256) {
        int it = u >> 6, lane = u & 63;
        int lrow = lane & 15, lgrp = lane >> 4;
        bf16x8 o;
#pragma unroll
        for (int e = 0; e < 8; ++e) {
            int us = it * 8 + e;
            int nt = us >> 2, j = us & 3;
            int m = (us < 36) ? (nt * 16 + lgrp * 4 + j) : 0;
            bf16_t v = L[lrow * 148 + m];
            o[e] = (us < 36) ? v : (bf16_t)0.f;
        }
        *(bf16x8*)(dst + it * 512 + lane * 8) = o;
    }
}

// ======================= kernel 1: QKV projection GEMM ======================
__global__ __launch_bounds__(256, 4)
void qkv_gemm(const float* __restrict__ x, const float* __restrict__ b_qkv,
              const bf16_t* __restrict__ wqkvS,
              bf16_t* __restrict__ Qg, bf16_t* __restrict__ Kg, bf16_t* __restrict__ Vt)
{
    __shared__ __align__(16) bf16_t Wb[2][6144];      // 24576 B
    __shared__ __align__(16) bf16_t T[4][1280];       // 10240 B (wave-private)
    const int tid  = threadIdx.x;
    const int lane = tid & 63;
    const int wave = tid >> 6;
    const int lrow = lane & 15;
    const int lgrp = lane >> 4;
    const int r0   = blockIdx.x * 128 + wave * 32;

    stage_chunk(&Wb[0][0], wqkvS, tid);   // chunk 0

    bf16x8 af[2][6];
#pragma unroll
    for (int tt = 0; tt < 2; ++tt)
#pragma unroll
        for (int ks = 0; ks < 6; ++ks) {
            const float* px = x + (size_t)(r0 + tt * 16 + lrow) * 192 + ks * 32 + lgrp * 8;
            f32x4 lo = *(const f32x4*)px;
            f32x4 hi = *(const f32x4*)(px + 4);
            bf16x8 v;
            v[0] = (bf16_t)lo[0]; v[1] = (bf16_t)lo[1]; v[2] = (bf16_t)lo[2]; v[3] = (bf16_t)lo[3];
            v[4] = (bf16_t)hi[0]; v[5] = (bf16_t)hi[1]; v[6] = (bf16_t)hi[2]; v[7] = (bf16_t)hi[3];
            af[tt][ks] = v;
        }
    __syncthreads();   // chunk 0 resident

    bf16_t* tl = &T[wave][0];

    for (int hc = 0; hc < 18; ++hc) {
        if (hc < 17) stage_chunk(&Wb[(hc + 1) & 1][0], wqkvS + (hc + 1) * 6144, tid);
        const bf16_t* wb = &Wb[hc & 1][0];

        f32x4 a[2][2];
        a[0][0] = f32x4{0.f,0.f,0.f,0.f}; a[0][1] = f32x4{0.f,0.f,0.f,0.f};
        a[1][0] = f32x4{0.f,0.f,0.f,0.f}; a[1][1] = f32x4{0.f,0.f,0.f,0.f};
#pragma unroll
        for (int ks = 0; ks < 6; ++ks) {
            bf16x8 wf0 = *(const bf16x8*)&wb[swz_elem(lrow,      ks * 32 + lgrp * 8)];
            bf16x8 wf1 = *(const bf16x8*)&wb[swz_elem(16 + lrow, ks * 32 + lgrp * 8)];
#pragma unroll
            for (int tt = 0; tt < 2; ++tt) {
                a[tt][0] = __builtin_amdgcn_mfma_f32_16x16x32_bf16(af[tt][ks], wf0, a[tt][0], 0, 0, 0);
                a[tt][1] = __builtin_amdgcn_mfma_f32_16x16x32_bf16(af[tt][ks], wf1, a[tt][1], 0, 0, 0);
            }
        }
        __syncthreads();   // chunk hc reads done; stage hc+1 drained

        float b0 = b_qkv[hc * 32 + lrow], b1 = b_qkv[hc * 32 + 16 + lrow];
        if (hc < 6) { b0 *= SCALE; b1 *= SCALE; }

        if (hc < 12) {
            const int h = (hc < 6) ? hc : hc - 6;
            bf16_t* dst = (hc < 6) ? Qg : Kg;
#pragma unroll
            for (int tt = 0; tt < 2; ++tt) {
#pragma unroll
                for (int j = 0; j < 4; ++j) {
                    tl[tt * 640 + (lgrp * 4 + j) * 40 + lrow]      = (bf16_t)(a[tt][0][j] + b0);
                    tl[tt * 640 + (lgrp * 4 + j) * 40 + 16 + lrow] = (bf16_t)(a[tt][1][j] + b1);
                }
                bf16x8 val = *(const bf16x8*)&tl[tt * 640 + lrow * 40 + lgrp * 8];
                int tk = r0 + tt * 16 + lrow, bw = tk / 144, n = tk % 144;
                *(bf16x8*)&dst[((size_t)(bw * 6 + h) * 144 + n) * 32 + lgrp * 8] = val;
            }
        } else {
            const int hv = hc - 12;
#pragma unroll
            for (int tt = 0; tt < 2; ++tt)
#pragma unroll
                for (int j = 0; j < 4; ++j) {
                    tl[(lrow) * 40      + tt * 16 + lgrp * 4 + j] = (bf16_t)(a[tt][0][j] + b0);
                    tl[(16 + lrow) * 40 + tt * 16 + lgrp * 4 + j] = (bf16_t)(a[tt][1][j] + b1);
                }
#pragma unroll
            for (int it = 0; it < 2; ++it) {
                int slot = it * 64 + lane;          // 128 slots = 32 d x 4 col-groups
                int d = slot >> 2, c = slot & 3;    // c*8 = 8-token group (8 | 144)
                int tk = r0 + c * 8, bw = tk / 144, n = tk % 144;
                bf16x8 val = *(const bf16x8*)&tl[d * 40 + c * 8];
                *(bf16x8*)&Vt[((size_t)(bw * 6 + hv) * 32 + d) * 160 + n] = val;
            }
        }
    }
}

// ======================= kernel 2: attention v10 (LDS-shared K/V) ===========
// grid 5952 x 192 thr (3 waves). block-task = (bw, h); K/V staged once into
// LDS via global_load_lds; wave w computes q-tiles {w, w+3, w+6}. One barrier.
__global__ __launch_bounds__(192, 3)
void earth_attn_v10(const bf16_t* __restrict__ Qg, const bf16_t* __restrict__ Kg,
                    const bf16_t* __restrict__ Vt,
                    const bf16_t* __restrict__ maskP, const bf16_t* __restrict__ biasP,
                    bf16_t* __restrict__ Og)
{
    __shared__ __align__(16) bf16_t Kl[4608];        //  9216 B  [144][32]
    __shared__ __align__(16) bf16_t Vl[5120];        // 10240 B  [32][160]
    __shared__ __align__(16) bf16_t P[3][16 * 168];  // 16128 B  wave-private
    const int tid  = threadIdx.x;
    const int lane = tid & 63;
    const int wave = tid >> 6;          // 0..2
    const int lrow = lane & 15;
    const int lgrp = lane >> 4;

    // bijective XCD swizzle: 5952 = 8 * 744 (contiguous chunk per XCD)
    const int orig = blockIdx.x;
    const int blk  = (orig & 7) * 744 + (orig >> 3);

    // ww-major task order (bias region L2-hot within an XCD chunk)
    const int ww = blk / 48;            // 0..123
    const int r1 = blk % 48;
    const int b  = r1 / 6;              // 0..7
    const int h  = r1 % 6;
    const int bw = b * 124 + ww;

    const size_t kbase = ((size_t)(bw * 6 + h) * 144) * 32;
    const size_t vbase = ((size_t)(bw * 6 + h) * 32) * 160;

    // ---- stage K (9 x 1KB) and V (10 x 1KB) into LDS, split across waves ---
    for (int c = wave; c < 9; c += 3)  stage_1k(Kl + c * 512, Kg + kbase + c * 512, lane);
    for (int c = wave; c < 10; c += 3) stage_1k(Vl + c * 512, Vt + vbase + c * 512, lane);

    // zero own P tail cols [144,160) once (never overwritten)
    bf16_t* pb = &P[wave][0];
    {
        uint2 z2 = make_uint2(0u, 0u);
        *(uint2*)&pb[lrow * 168 + 144 + lgrp * 4] = z2;
    }
    __syncthreads();   // drains global_load_lds (vmcnt 0 before barrier)

    const bf16_t* bpB = biasP + (size_t)(ww * 6 + h) * 9 * 2560 + lane * 8;
    const bf16_t* mpB = maskP + (size_t)bw * 9 * 2560 + lane * 8;
    bf16_t* ogp = Og + ((size_t)bw * 144) * 192 + h * 32 + lgrp * 8;

#pragma unroll 1
    for (int i = 0; i < 3; ++i) {
        const int t = wave + i * 3;     // this wave's q-tile

        // ---- bias/mask (bf16 permuted: 10 contiguous 1KB wave-loads) -------
        bf16x8 bvv[5], mvv[5];
#pragma unroll
        for (int it = 0; it < 5; ++it) {
            bvv[it] = *(const bf16x8*)(bpB + (size_t)t * 2560 + it * 512);
            mvv[it] = *(const bf16x8*)(mpB + (size_t)t * 2560 + it * 512);
        }
        bf16x8 qa = *(const bf16x8*)&Qg[kbase + (size_t)(t * 16 + lrow) * 32 + lgrp * 8];

        f32x4 s[9];
#pragma unroll
        for (int nt = 0; nt < 9; ++nt)
#pragma unroll
            for (int j = 0; j < 4; ++j) {
                const int u = nt * 4 + j;
                s[nt][j] = (float)bvv[u >> 3][u & 7] + (float)mvv[u >> 3][u & 7];
            }

        // ---- S^T = K Q^T + C-init (K fragments from LDS) --------------------
#pragma unroll
        for (int nt = 0; nt < 9; ++nt) {
            bf16x8 ka = *(const bf16x8*)&Kl[(nt * 16 + lrow) * 32 + lgrp * 8];
            s[nt] = __builtin_amdgcn_mfma_f32_16x16x32_bf16(ka, qa, s[nt], 0, 0, 0);
        }

        // ---- softmax (lane owns q-row t*16+lrow; m spread over lgrp) --------
        float mx = -1e30f;
#pragma unroll
        for (int nt = 0; nt < 9; ++nt)
#pragma unroll
            for (int j = 0; j < 4; ++j) mx = fmaxf(mx, s[nt][j]);
        mx = fmaxf(mx, __shfl_xor(mx, 16, 64));
        mx = fmaxf(mx, __shfl_xor(mx, 32, 64));
        float sum = 0.f;
#pragma unroll
        for (int nt = 0; nt < 9; ++nt)
#pragma unroll
            for (int j = 0; j < 4; ++j) { float e = __expf(s[nt][j] - mx); s[nt][j] = e; sum += e; }
        sum += __shfl_xor(sum, 16, 64);
        sum += __shfl_xor(sum, 32, 64);
        const float rinv = 1.0f / sum;

        // ---- P -> own LDS tile (tail already zero) ---------------------------
#pragma unroll
        for (int nt = 0; nt < 9; ++nt) {
            bf16x4 pw;
#pragma unroll
            for (int j = 0; j < 4; ++j) pw[j] = (bf16_t)(s[nt][j] * rinv);
            *(bf16x4*)&pb[lrow * 168 + nt * 16 + lgrp * 4] = pw;
        }

        // ---- PV: P fragments + V fragments from LDS --------------------------
        f32x4 o0{0.f, 0.f, 0.f, 0.f}, o1{0.f, 0.f, 0.f, 0.f};
#pragma unroll
        for (int ks = 0; ks < 5; ++ks) {
            bf16x8 pa = *(const bf16x8*)&pb[lrow * 168 + ks * 32 + lgrp * 8];
            bf16x8 v0 = *(const bf16x8*)&Vl[lrow * 160 + ks * 32 + lgrp * 8];
            bf16x8 v1 = *(const bf16x8*)&Vl[(16 + lrow) * 160 + ks * 32 + lgrp * 8];
            o0 = __builtin_amdgcn_mfma_f32_16x16x32_bf16(pa, v0, o0, 0, 0, 0);
            o1 = __builtin_amdgcn_mfma_f32_16x16x32_bf16(pa, v1, o1, 0, 0, 0);
        }

        // ---- O transpose via pb reuse (own rows; per-wave in-order), store ---
#pragma unroll
        for (int j = 0; j < 4; ++j) {
            pb[(lgrp * 4 + j) * 168 + lrow]      = (bf16_t)o0[j];
            pb[(lgrp * 4 + j) * 168 + 16 + lrow] = (bf16_t)o1[j];
        }
        bf16x8 ov = *(const bf16x8*)&pb[lrow * 168 + lgrp * 8];
        *(bf16x8*)(ogp + (size_t)(t * 16 + lrow) * 192) = ov;
    }
}

// ======================= fallback attention (fp32 bias/mask, R11) ===========
__global__ __launch_bounds__(256, 2)
void earth_attn_v7(const bf16_t* __restrict__ Qg, const bf16_t* __restrict__ Kg,
                   const bf16_t* __restrict__ Vt,
                   const float* __restrict__ mask, const float* __restrict__ bias,
                   bf16_t* __restrict__ Og)
{
    __shared__ bf16_t P[4][16 * 168];
    const int tid  = threadIdx.x;
    const int lane = tid & 63;
    const int wave = tid >> 6;
    const int lrow = lane & 15;
    const int lgrp = lane >> 4;
    const int orig = blockIdx.x;
    const int blk  = (orig & 7) * 186 + (orig >> 3);
    const int wid = blk * 4 + wave;
    const int ww  = wid / 48;
    const int r1  = wid % 48;
    const int b   = r1 / 6;
    const int h   = r1 % 6;
    const int bw  = b * 124 + ww;
    const size_t kbase = ((size_t)(bw * 6 + h) * 144) * 32;
    const size_t vbase = ((size_t)(bw * 6 + h) * 32) * 160;

    bf16x8 ka[9];
#pragma unroll
    for (int nt = 0; nt < 9; ++nt)
        ka[nt] = *(const bf16x8*)&Kg[kbase + (size_t)(nt * 16 + lrow) * 32 + lgrp * 8];
    bf16x8 va0[5], va1[5];
#pragma unroll
    for (int ks = 0; ks < 5; ++ks) {
        va0[ks] = *(const bf16x8*)&Vt[vbase + (size_t)lrow * 160 + ks * 32 + lgrp * 8];
        va1[ks] = *(const bf16x8*)&Vt[vbase + (size_t)(16 + lrow) * 160 + ks * 32 + lgrp * 8];
    }
    const float* bp_base = bias + (size_t)(ww * 6 + h) * 144 * 144;
    const float* mp_base = mask + (size_t)bw * 144 * 144;
    bf16_t* pb = &P[wave][0];
    bf16_t* ogp = Og + ((size_t)bw * 144) * 192 + h * 32 + lgrp * 8;
    bf16x8 qa = *(const bf16x8*)&Qg[kbase + (size_t)lrow * 32 + lgrp * 8];
    f32x4 bv[9], mv[9];
    {
        const float* bp = bp_base + (size_t)lrow * 144;
        const float* mp = mp_base + (size_t)lrow * 144;
#pragma unroll
        for (int nt = 0; nt < 9; ++nt) {
            bv[nt] = *(const f32x4*)(bp + nt * 16 + lgrp * 4);
            mv[nt] = *(const f32x4*)(mp + nt * 16 + lgrp * 4);
        }
    }
#pragma unroll 1
    for (int t = 0; t < 9; ++t) {
        f32x4 s[9];
#pragma unroll
        for (int nt = 0; nt < 9; ++nt) s[nt] = bv[nt] + mv[nt];
        const int tn = (t < 8) ? t + 1 : 8;
        bf16x8 qa_n = *(const bf16x8*)&Qg[kbase + (size_t)(tn * 16 + lrow) * 32 + lgrp * 8];
        {
            const float* bp = bp_base + (size_t)(tn * 16 + lrow) * 144;
            const float* mp = mp_base + (size_t)(tn * 16 + lrow) * 144;
#pragma unroll
            for (int nt = 0; nt < 9; ++nt) {
                bv[nt] = *(const f32x4*)(bp + nt * 16 + lgrp * 4);
                mv[nt] = *(const f32x4*)(mp + nt * 16 + lgrp * 4);
            }
        }
#pragma unroll
        for (int nt = 0; nt < 9; ++nt)
            s[nt] = __builtin_amdgcn_mfma_f32_16x16x32_bf16(ka[nt], qa, s[nt], 0, 0, 0);
        float mx = -1e30f;
#pragma unroll
        for (int nt = 0; nt < 9; ++nt)
#pragma unroll
            for (int j = 0; j < 4; ++j) mx = fmaxf(mx, s[nt][j]);
        mx = fmaxf(mx, __shfl_xor(mx, 16, 64));
        mx = fmaxf(mx, __shfl_xor(mx, 32, 64));
        float sum = 0.f;
#pragma unroll
        for (int nt = 0; nt < 9; ++nt)
#pragma unroll
            for (int j = 0; j < 4; ++j) { float e = __expf(s[nt][j] - mx); s[nt][j] = e; sum += e; }
        sum += __shfl_xor(sum, 16, 64);
        sum += __shfl_xor(sum, 32, 64);
        const float rinv = 1.0f / sum;
#pragma unroll
        for (int nt = 0; nt < 9; ++nt) {
            bf16x4 pw;
#pragma unroll
            for (int j = 0; j < 4; ++j) pw[j] = (bf16_t)(s[nt][j] * rinv);
            *(bf16x4*)&pb[lrow * 168 + nt * 16 + lgrp * 4] = pw;
        }
        {
            uint2 z2 = make_uint2(0u, 0u);
            *(uint2*)&pb[lrow * 168 + 144 + lgrp * 4] = z2;
        }
        bf16x8 pa[5];
#pragma unroll
        for (int ks = 0; ks < 5; ++ks)
            pa[ks] = *(const bf16x8*)&pb[lrow * 168 + ks * 32 + lgrp * 8];
#pragma unroll
        for (int ks = 0; ks < 5; ++ks) PIN(pa[ks]);
        f32x4 o0{0.f, 0.f, 0.f, 0.f}, o1{0.f, 0.f, 0.f, 0.f};
#pragma unroll
        for (int ks = 0; ks < 5; ++ks) {
            o0 = __builtin_amdgcn_mfma_f32_16x16x32_bf16(pa[ks], va0[ks], o0, 0, 0, 0);
            o1 = __builtin_amdgcn_mfma_f32_16x16x32_bf16(pa[ks], va1[ks], o1, 0, 0, 0);
        }
#pragma unroll
        for (int j = 0; j < 4; ++j) {
            pb[(lgrp * 4 + j) * 168 + lrow]      = (bf16_t)o0[j];
            pb[(lgrp * 4 + j) * 168 + 16 + lrow] = (bf16_t)o1[j];
        }
        bf16x8 ov = *(const bf16x8*)&pb[lrow * 168 + lgrp * 8];
        *(bf16x8*)(ogp + (size_t)(t * 16 + lrow) * 192) = ov;
        qa = qa_n;
    }
}

// ======================= kernel 3: out-projection GEMM ======================
__global__ __launch_bounds__(256, 4)
void out_proj(const bf16_t* __restrict__ Og, const bf16_t* __restrict__ woutS,
              const float* __restrict__ b_out, float* __restrict__ out)
{
    __shared__ __align__(16) bf16_t Wb[2][6144];
    const int tid  = threadIdx.x;
    const int lane = tid & 63;
    const int wave = tid >> 6;
    const int lrow = lane & 15;
    const int lgrp = lane >> 4;
    const size_t row0 = (size_t)blockIdx.x * 64 + wave * 16;

    stage_chunk(&Wb[0][0], woutS, tid);

    bf16x8 af[6];
#pragma unroll
    for (int ks = 0; ks < 6; ++ks)
        af[ks] = *(const bf16x8*)(Og + (row0 + lrow) * 192 + ks * 32 + lgrp * 8);
    __syncthreads();

#pragma unroll
    for (int c = 0; c < 6; ++c) {
        if (c < 5) stage_chunk(&Wb[(c + 1) & 1][0], woutS + (c + 1) * 6144, tid);
        const bf16_t* wb = &Wb[c & 1][0];
        float b0 = b_out[c * 32 + lrow], b1 = b_out[c * 32 + 16 + lrow];
        f32x4 a0{b0, b0, b0, b0}, a1{b1, b1, b1, b1};
#pragma unroll
        for (int ks = 0; ks < 6; ++ks) {
            bf16x8 wf0 = *(const bf16x8*)&wb[swz_elem(lrow,      ks * 32 + lgrp * 8)];
            bf16x8 wf1 = *(const bf16x8*)&wb[swz_elem(16 + lrow, ks * 32 + lgrp * 8)];
            a0 = __builtin_amdgcn_mfma_f32_16x16x32_bf16(af[ks], wf0, a0, 0, 0, 0);
            a1 = __builtin_amdgcn_mfma_f32_16x16x32_bf16(af[ks], wf1, a1, 0, 0, 0);
        }
        __syncthreads();
#pragma unroll
        for (int j = 0; j < 4; ++j) {
            out[(row0 + lgrp * 4 + j) * 192 + c * 32 + lrow]      = a0[j];
            out[(row0 + lgrp * 4 + j) * 192 + c * 32 + 16 + lrow] = a1[j];
        }
    }
}

// ======================= launch =============================================
extern "C" void kernel_launch(void* const* d_in, const int* in_sizes, int n_in,
                              void* d_out, int out_size, void* d_ws, size_t ws_size,
                              hipStream_t stream) {
    const float* x     = (const float*)d_in[0];
    const float* mask  = (const float*)d_in[1];
    const float* w_qkv = (const float*)d_in[2];
    const float* b_qkv = (const float*)d_in[3];
    const float* bias  = (const float*)d_in[4];
    const float* w_out = (const float*)d_in[5];
    const float* b_out = (const float*)d_in[6];

    bf16_t* wqkvS = (bf16_t*)d_ws;                     //    110,592 elems
    bf16_t* woutS = wqkvS + 576 * 192;                 //     36,864
    bf16_t* Qg    = woutS + 192 * 192;                 // 27,426,816
    bf16_t* Kg    = Qg + (size_t)992 * 6 * 144 * 32;   // 27,426,816
    bf16_t* Vt    = Kg + (size_t)992 * 6 * 144 * 32;   // 30,474,240
    bf16_t* Og    = Vt + (size_t)992 * 6 * 32 * 160;   // 27,426,816
    bf16_t* biasP = Og + (size_t)992 * 144 * 192;      // 17,141,760
    bf16_t* maskP = biasP + (size_t)6696 * 2560;       // 22,855,680

    const size_t need_v10 = ((size_t)112902144 + 17141760 + 22855680) * 2;   // ~306 MB

    prep_weights<<<dim3(432), dim3(256), 0, stream>>>(w_qkv, w_out, wqkvS, woutS);
    qkv_gemm<<<dim3(1116), dim3(256), 0, stream>>>(x, b_qkv, wqkvS, Qg, Kg, Vt);

    if (ws_size >= need_v10) {
        prep_bm2<<<dim3(15624), dim3(256), 0, stream>>>(bias, mask, biasP, maskP);
        earth_attn_v10<<<dim3(5952), dim3(192), 0, stream>>>(Qg, Kg, Vt, maskP, biasP, Og);
    } else {
        earth_attn_v7<<<dim3(1488), dim3(256), 0, stream>>>(Qg, Kg, Vt, mask, bias, Og);
    }
    out_proj<<<dim3(2232), dim3(256), 0, stream>>>(Og, woutS, b_out, (float*)d_out);
}

// Round 15
// 259.554 us; speedup vs baseline: 1.0986x; 1.0254x over previous
//
#include <hip/hip_runtime.h>
#include <hip/hip_bf16.h>

typedef __bf16 bf16_t;
typedef bf16_t bf16x8 __attribute__((ext_vector_type(8)));
typedef bf16_t bf16x4 __attribute__((ext_vector_type(4)));
typedef float f32x4 __attribute__((ext_vector_type(4)));

#define SCALE 0.17677669529663687f  // 32^-0.5

// keep a loaded value live / pinned at this program point
#define PIN(x) asm volatile("" : "+v"(x))

// Swizzled element offset within a 32x192 bf16 chunk image (row stride 384 B).
__device__ __forceinline__ int swz_elem(int r, int c) {
    int g = c >> 3;
    return r * 192 + ((g >> 3) << 6) + (((g & 7) ^ (r & 7)) << 3) + (c & 7);
}

// async global->LDS: 16B per lane, linear dest (lane-order = image order)
__device__ __forceinline__ void stage_chunk(bf16_t* dst, const bf16_t* src, int tid) {
#pragma unroll
    for (int it = 0; it < 3; ++it) {
        int off = (it * 256 + tid) * 8;   // 3*256*8 = 6144 elems = 12288 B
        __builtin_amdgcn_global_load_lds(
            (const __attribute__((address_space(1))) unsigned int*)(src + off),
            (__attribute__((address_space(3))) unsigned int*)(dst + off),
            16, 0, 0);
    }
}

// stage one 1024B chunk (64 lanes x 16B), per-lane matching offsets
__device__ __forceinline__ void stage_1k(bf16_t* dst, const bf16_t* src, int lane) {
    __builtin_amdgcn_global_load_lds(
        (const __attribute__((address_space(1))) unsigned int*)(src + lane * 8),
        (__attribute__((address_space(3))) unsigned int*)(dst + lane * 8),
        16, 0, 0);
}

// ======================= prep: weights -> swizzled bf16 chunk images ========
__global__ void prep_weights(const float* __restrict__ w_qkv, const float* __restrict__ w_out,
                             bf16_t* __restrict__ wqkvS, bf16_t* __restrict__ woutS) {
    int i = blockIdx.x * 256 + threadIdx.x;
    if (i < 576 * 192) {
        int o = i / 192, k = i % 192;
        float v = w_qkv[k * 576 + o];
        if (o < 192) v *= SCALE;
        wqkvS[(o >> 5) * 6144 + swz_elem(o & 31, k)] = (bf16_t)v;
    }
    if (i < 192 * 192) {
        int o = i / 192, k = i % 192;
        woutS[(o >> 5) * 6144 + swz_elem(o & 31, k)] = (bf16_t)w_out[k * 192 + o];
    }
}

// ======================= prep: bias/mask -> bf16 permuted (coalesced) =======
__global__ __launch_bounds__(256, 8)
void prep_bm2(const float* __restrict__ bias, const float* __restrict__ mask,
              bf16_t* __restrict__ biasP, bf16_t* __restrict__ maskP)
{
    __shared__ bf16_t L[16 * 148];   // 4736 B
    int blk = blockIdx.x;            // [0,6696) bias, [6696,15624) mask
    bool isMask = blk >= 6696;
    int region = isMask ? blk - 6696 : blk;
    int rg = region / 9, t = region % 9;
    const float* src = (isMask ? mask : bias) + ((size_t)rg * 144 + t * 16) * 144;
    bf16_t* dst = (isMask ? maskP : biasP) + (size_t)region * 2560;
    const int tid = threadIdx.x;

    for (int i = tid; i < 576; i += 256) {
        int row = i / 36, seg = i % 36;
        f32x4 v = *(const f32x4*)(src + row * 144 + seg * 4);
        bf16x4 o;
        o[0] = (bf16_t)v[0]; o[1] = (bf16_t)v[1]; o[2] = (bf16_t)v[2]; o[3] = (bf16_t)v[3];
        *(bf16x4*)&L[row * 148 + seg * 4] = o;
    }
    __syncthreads();

    for (int u = tid; u < 320; u += 256) {
        int it = u >> 6, lane = u & 63;
        int lrow = lane & 15, lgrp = lane >> 4;
        bf16x8 o;
#pragma unroll
        for (int e = 0; e < 8; ++e) {
            int us = it * 8 + e;
            int nt = us >> 2, j = us & 3;
            int m = (us < 36) ? (nt * 16 + lgrp * 4 + j) : 0;
            bf16_t v = L[lrow * 148 + m];
            o[e] = (us < 36) ? v : (bf16_t)0.f;
        }
        *(bf16x8*)(dst + it * 512 + lane * 8) = o;
    }
}

// ======================= kernel 1: QKV GEMM (rotated, 3-buf pipeline) =======
// grid 1116 x 256 thr. Chunk order rotated by blockIdx%18 (breaks the L2
// same-address storm). Chunks staged 2-deep into a 3-buffer LDS rotation with
// counted vmcnt (never 0 mid-loop) + raw s_barrier: prefetch survives the
// barrier. Per-wave vmcnt events: 3 stage-loads + 2 stores per iteration.
__global__ __launch_bounds__(256, 4)
void qkv_gemm(const float* __restrict__ x, const float* __restrict__ b_qkv,
              const bf16_t* __restrict__ wqkvS,
              bf16_t* __restrict__ Qg, bf16_t* __restrict__ Kg, bf16_t* __restrict__ Vt)
{
    __shared__ __align__(16) bf16_t Wb[3][6144];      // 36864 B (3-deep)
    __shared__ __align__(16) bf16_t T[4][1280];       // 10240 B (wave-private)
    __shared__ float bl[576];                          //  2304 B bias copy
    const int tid  = threadIdx.x;
    const int lane = tid & 63;
    const int wave = tid >> 6;
    const int lrow = lane & 15;
    const int lgrp = lane >> 4;
    const int r0   = blockIdx.x * 128 + wave * 32;
    const int c0   = blockIdx.x % 18;                  // chunk rotation

    // bias -> LDS (once)
    for (int i = tid; i < 576; i += 256) bl[i] = b_qkv[i];

    // X fragments (fp32 -> bf16)
    bf16x8 af[2][6];
#pragma unroll
    for (int tt = 0; tt < 2; ++tt)
#pragma unroll
        for (int ks = 0; ks < 6; ++ks) {
            const float* px = x + (size_t)(r0 + tt * 16 + lrow) * 192 + ks * 32 + lgrp * 8;
            f32x4 lo = *(const f32x4*)px;
            f32x4 hi = *(const f32x4*)(px + 4);
            bf16x8 v;
            v[0] = (bf16_t)lo[0]; v[1] = (bf16_t)lo[1]; v[2] = (bf16_t)lo[2]; v[3] = (bf16_t)lo[3];
            v[4] = (bf16_t)hi[0]; v[5] = (bf16_t)hi[1]; v[6] = (bf16_t)hi[2]; v[7] = (bf16_t)hi[3];
            af[tt][ks] = v;
        }

    // stage chunks c0, c0+1 (depth-2 prologue)
    stage_chunk(&Wb[0][0], wqkvS + c0 * 6144, tid);
    {
        int nc = c0 + 1; if (nc >= 18) nc -= 18;
        stage_chunk(&Wb[1][0], wqkvS + nc * 6144, tid);
    }
    // drain buf0's 3 loads (allow buf1's 3); lgkm for bl visibility
    asm volatile("s_waitcnt vmcnt(3) lgkmcnt(0)" ::: "memory");
    __builtin_amdgcn_sched_barrier(0);
    __builtin_amdgcn_s_barrier();
    __builtin_amdgcn_sched_barrier(0);

    bf16_t* tl = &T[wave][0];

#pragma unroll 1
    for (int i = 0; i < 18; ++i) {
        int hc = c0 + i; if (hc >= 18) hc -= 18;

        if (i <= 15) {   // stage chunk i+2 into buf (i+2)%3
            int nc = c0 + i + 2; if (nc >= 18) nc -= 18;
            stage_chunk(&Wb[(i + 2) % 3][0], wqkvS + nc * 6144, tid);
        }
        const bf16_t* wb = &Wb[i % 3][0];

        f32x4 a[2][2];
        a[0][0] = f32x4{0.f,0.f,0.f,0.f}; a[0][1] = f32x4{0.f,0.f,0.f,0.f};
        a[1][0] = f32x4{0.f,0.f,0.f,0.f}; a[1][1] = f32x4{0.f,0.f,0.f,0.f};
#pragma unroll
        for (int ks = 0; ks < 6; ++ks) {
            bf16x8 wf0 = *(const bf16x8*)&wb[swz_elem(lrow,      ks * 32 + lgrp * 8)];
            bf16x8 wf1 = *(const bf16x8*)&wb[swz_elem(16 + lrow, ks * 32 + lgrp * 8)];
#pragma unroll
            for (int tt = 0; tt < 2; ++tt) {
                a[tt][0] = __builtin_amdgcn_mfma_f32_16x16x32_bf16(af[tt][ks], wf0, a[tt][0], 0, 0, 0);
                a[tt][1] = __builtin_amdgcn_mfma_f32_16x16x32_bf16(af[tt][ks], wf1, a[tt][1], 0, 0, 0);
            }
        }

        float b0 = bl[hc * 32 + lrow], b1 = bl[hc * 32 + 16 + lrow];
        if (hc < 6) { b0 *= SCALE; b1 *= SCALE; }

        if (hc < 12) {
            // Q/K: per-16-row T transpose, coalesced row-major store (2 stores)
            const int h = (hc < 6) ? hc : hc - 6;
            bf16_t* dst = (hc < 6) ? Qg : Kg;
#pragma unroll
            for (int tt = 0; tt < 2; ++tt) {
#pragma unroll
                for (int j = 0; j < 4; ++j) {
                    tl[tt * 640 + (lgrp * 4 + j) * 40 + lrow]      = (bf16_t)(a[tt][0][j] + b0);
                    tl[tt * 640 + (lgrp * 4 + j) * 40 + 16 + lrow] = (bf16_t)(a[tt][1][j] + b1);
                }
                bf16x8 val = *(const bf16x8*)&tl[tt * 640 + lrow * 40 + lgrp * 8];
                int tk = r0 + tt * 16 + lrow, bw = tk / 144, n = tk % 144;
                *(bf16x8*)&dst[((size_t)(bw * 6 + h) * 144 + n) * 32 + lgrp * 8] = val;
            }
        } else {
            // V: d-major tile in T, store transposed [d][n] (2 stores)
            const int hv = hc - 12;
#pragma unroll
            for (int tt = 0; tt < 2; ++tt)
#pragma unroll
                for (int j = 0; j < 4; ++j) {
                    tl[(lrow) * 40      + tt * 16 + lgrp * 4 + j] = (bf16_t)(a[tt][0][j] + b0);
                    tl[(16 + lrow) * 40 + tt * 16 + lgrp * 4 + j] = (bf16_t)(a[tt][1][j] + b1);
                }
#pragma unroll
            for (int it = 0; it < 2; ++it) {
                int slot = it * 64 + lane;          // 128 slots = 32 d x 4 col-groups
                int d = slot >> 2, c = slot & 3;    // c*8 = 8-token group (8 | 144)
                int tk = r0 + c * 8, bw = tk / 144, n = tk % 144;
                bf16x8 val = *(const bf16x8*)&tl[d * 40 + c * 8];
                *(bf16x8*)&Vt[((size_t)(bw * 6 + hv) * 32 + d) * 160 + n] = val;
            }
        }

        // counted-vmcnt barrier: drain buf (i+1)%3's stage, keep newer in flight.
        // queue (old->new): [target stage 3][prev stores 2?][next stage 3?][cur stores 2]
        if (i < 17) {
            if (i == 0)       { asm volatile("s_waitcnt vmcnt(5)" ::: "memory"); }
            else if (i <= 15) { asm volatile("s_waitcnt vmcnt(7)" ::: "memory"); }
            else              { asm volatile("s_waitcnt vmcnt(4)" ::: "memory"); }
            __builtin_amdgcn_sched_barrier(0);
            __builtin_amdgcn_s_barrier();
            __builtin_amdgcn_sched_barrier(0);
        }
    }
}

// ======================= kernel 2: attention v10 (LDS-shared K/V) ===========
__global__ __launch_bounds__(192, 3)
void earth_attn_v10(const bf16_t* __restrict__ Qg, const bf16_t* __restrict__ Kg,
                    const bf16_t* __restrict__ Vt,
                    const bf16_t* __restrict__ maskP, const bf16_t* __restrict__ biasP,
                    bf16_t* __restrict__ Og)
{
    __shared__ __align__(16) bf16_t Kl[4608];        //  9216 B  [144][32]
    __shared__ __align__(16) bf16_t Vl[5120];        // 10240 B  [32][160]
    __shared__ __align__(16) bf16_t P[3][16 * 168];  // 16128 B  wave-private
    const int tid  = threadIdx.x;
    const int lane = tid & 63;
    const int wave = tid >> 6;          // 0..2
    const int lrow = lane & 15;
    const int lgrp = lane >> 4;

    const int orig = blockIdx.x;
    const int blk  = (orig & 7) * 744 + (orig >> 3);   // 5952 = 8*744

    const int ww = blk / 48;
    const int r1 = blk % 48;
    const int b  = r1 / 6;
    const int h  = r1 % 6;
    const int bw = b * 124 + ww;

    const size_t kbase = ((size_t)(bw * 6 + h) * 144) * 32;
    const size_t vbase = ((size_t)(bw * 6 + h) * 32) * 160;

    for (int c = wave; c < 9; c += 3)  stage_1k(Kl + c * 512, Kg + kbase + c * 512, lane);
    for (int c = wave; c < 10; c += 3) stage_1k(Vl + c * 512, Vt + vbase + c * 512, lane);

    bf16_t* pb = &P[wave][0];
    {
        uint2 z2 = make_uint2(0u, 0u);
        *(uint2*)&pb[lrow * 168 + 144 + lgrp * 4] = z2;
    }
    __syncthreads();

    const bf16_t* bpB = biasP + (size_t)(ww * 6 + h) * 9 * 2560 + lane * 8;
    const bf16_t* mpB = maskP + (size_t)bw * 9 * 2560 + lane * 8;
    bf16_t* ogp = Og + ((size_t)bw * 144) * 192 + h * 32 + lgrp * 8;

#pragma unroll 1
    for (int i = 0; i < 3; ++i) {
        const int t = wave + i * 3;

        bf16x8 bvv[5], mvv[5];
#pragma unroll
        for (int it = 0; it < 5; ++it) {
            bvv[it] = *(const bf16x8*)(bpB + (size_t)t * 2560 + it * 512);
            mvv[it] = *(const bf16x8*)(mpB + (size_t)t * 2560 + it * 512);
        }
        bf16x8 qa = *(const bf16x8*)&Qg[kbase + (size_t)(t * 16 + lrow) * 32 + lgrp * 8];

        f32x4 s[9];
#pragma unroll
        for (int nt = 0; nt < 9; ++nt)
#pragma unroll
            for (int j = 0; j < 4; ++j) {
                const int u = nt * 4 + j;
                s[nt][j] = (float)bvv[u >> 3][u & 7] + (float)mvv[u >> 3][u & 7];
            }

#pragma unroll
        for (int nt = 0; nt < 9; ++nt) {
            bf16x8 ka = *(const bf16x8*)&Kl[(nt * 16 + lrow) * 32 + lgrp * 8];
            s[nt] = __builtin_amdgcn_mfma_f32_16x16x32_bf16(ka, qa, s[nt], 0, 0, 0);
        }

        float mx = -1e30f;
#pragma unroll
        for (int nt = 0; nt < 9; ++nt)
#pragma unroll
            for (int j = 0; j < 4; ++j) mx = fmaxf(mx, s[nt][j]);
        mx = fmaxf(mx, __shfl_xor(mx, 16, 64));
        mx = fmaxf(mx, __shfl_xor(mx, 32, 64));
        float sum = 0.f;
#pragma unroll
        for (int nt = 0; nt < 9; ++nt)
#pragma unroll
            for (int j = 0; j < 4; ++j) { float e = __expf(s[nt][j] - mx); s[nt][j] = e; sum += e; }
        sum += __shfl_xor(sum, 16, 64);
        sum += __shfl_xor(sum, 32, 64);
        const float rinv = 1.0f / sum;

#pragma unroll
        for (int nt = 0; nt < 9; ++nt) {
            bf16x4 pw;
#pragma unroll
            for (int j = 0; j < 4; ++j) pw[j] = (bf16_t)(s[nt][j] * rinv);
            *(bf16x4*)&pb[lrow * 168 + nt * 16 + lgrp * 4] = pw;
        }

        f32x4 o0{0.f, 0.f, 0.f, 0.f}, o1{0.f, 0.f, 0.f, 0.f};
#pragma unroll
        for (int ks = 0; ks < 5; ++ks) {
            bf16x8 pa = *(const bf16x8*)&pb[lrow * 168 + ks * 32 + lgrp * 8];
            bf16x8 v0 = *(const bf16x8*)&Vl[lrow * 160 + ks * 32 + lgrp * 8];
            bf16x8 v1 = *(const bf16x8*)&Vl[(16 + lrow) * 160 + ks * 32 + lgrp * 8];
            o0 = __builtin_amdgcn_mfma_f32_16x16x32_bf16(pa, v0, o0, 0, 0, 0);
            o1 = __builtin_amdgcn_mfma_f32_16x16x32_bf16(pa, v1, o1, 0, 0, 0);
        }

#pragma unroll
        for (int j = 0; j < 4; ++j) {
            pb[(lgrp * 4 + j) * 168 + lrow]      = (bf16_t)o0[j];
            pb[(lgrp * 4 + j) * 168 + 16 + lrow] = (bf16_t)o1[j];
        }
        bf16x8 ov = *(const bf16x8*)&pb[lrow * 168 + lgrp * 8];
        *(bf16x8*)(ogp + (size_t)(t * 16 + lrow) * 192) = ov;
    }
}

// ======================= fallback attention (fp32 bias/mask, R11) ===========
__global__ __launch_bounds__(256, 2)
void earth_attn_v7(const bf16_t* __restrict__ Qg, const bf16_t* __restrict__ Kg,
                   const bf16_t* __restrict__ Vt,
                   const float* __restrict__ mask, const float* __restrict__ bias,
                   bf16_t* __restrict__ Og)
{
    __shared__ bf16_t P[4][16 * 168];
    const int tid  = threadIdx.x;
    const int lane = tid & 63;
    const int wave = tid >> 6;
    const int lrow = lane & 15;
    const int lgrp = lane >> 4;
    const int orig = blockIdx.x;
    const int blk  = (orig & 7) * 186 + (orig >> 3);
    const int wid = blk * 4 + wave;
    const int ww  = wid / 48;
    const int r1  = wid % 48;
    const int b   = r1 / 6;
    const int h   = r1 % 6;
    const int bw  = b * 124 + ww;
    const size_t kbase = ((size_t)(bw * 6 + h) * 144) * 32;
    const size_t vbase = ((size_t)(bw * 6 + h) * 32) * 160;

    bf16x8 ka[9];
#pragma unroll
    for (int nt = 0; nt < 9; ++nt)
        ka[nt] = *(const bf16x8*)&Kg[kbase + (size_t)(nt * 16 + lrow) * 32 + lgrp * 8];
    bf16x8 va0[5], va1[5];
#pragma unroll
    for (int ks = 0; ks < 5; ++ks) {
        va0[ks] = *(const bf16x8*)&Vt[vbase + (size_t)lrow * 160 + ks * 32 + lgrp * 8];
        va1[ks] = *(const bf16x8*)&Vt[vbase + (size_t)(16 + lrow) * 160 + ks * 32 + lgrp * 8];
    }
    const float* bp_base = bias + (size_t)(ww * 6 + h) * 144 * 144;
    const float* mp_base = mask + (size_t)bw * 144 * 144;
    bf16_t* pb = &P[wave][0];
    bf16_t* ogp = Og + ((size_t)bw * 144) * 192 + h * 32 + lgrp * 8;
    bf16x8 qa = *(const bf16x8*)&Qg[kbase + (size_t)lrow * 32 + lgrp * 8];
    f32x4 bv[9], mv[9];
    {
        const float* bp = bp_base + (size_t)lrow * 144;
        const float* mp = mp_base + (size_t)lrow * 144;
#pragma unroll
        for (int nt = 0; nt < 9; ++nt) {
            bv[nt] = *(const f32x4*)(bp + nt * 16 + lgrp * 4);
            mv[nt] = *(const f32x4*)(mp + nt * 16 + lgrp * 4);
        }
    }
#pragma unroll 1
    for (int t = 0; t < 9; ++t) {
        f32x4 s[9];
#pragma unroll
        for (int nt = 0; nt < 9; ++nt) s[nt] = bv[nt] + mv[nt];
        const int tn = (t < 8) ? t + 1 : 8;
        bf16x8 qa_n = *(const bf16x8*)&Qg[kbase + (size_t)(tn * 16 + lrow) * 32 + lgrp * 8];
        {
            const float* bp = bp_base + (size_t)(tn * 16 + lrow) * 144;
            const float* mp = mp_base + (size_t)(tn * 16 + lrow) * 144;
#pragma unroll
            for (int nt = 0; nt < 9; ++nt) {
                bv[nt] = *(const f32x4*)(bp + nt * 16 + lgrp * 4);
                mv[nt] = *(const f32x4*)(mp + nt * 16 + lgrp * 4);
            }
        }
#pragma unroll
        for (int nt = 0; nt < 9; ++nt)
            s[nt] = __builtin_amdgcn_mfma_f32_16x16x32_bf16(ka[nt], qa, s[nt], 0, 0, 0);
        float mx = -1e30f;
#pragma unroll
        for (int nt = 0; nt < 9; ++nt)
#pragma unroll
            for (int j = 0; j < 4; ++j) mx = fmaxf(mx, s[nt][j]);
        mx = fmaxf(mx, __shfl_xor(mx, 16, 64));
        mx = fmaxf(mx, __shfl_xor(mx, 32, 64));
        float sum = 0.f;
#pragma unroll
        for (int nt = 0; nt < 9; ++nt)
#pragma unroll
            for (int j = 0; j < 4; ++j) { float e = __expf(s[nt][j] - mx); s[nt][j] = e; sum += e; }
        sum += __shfl_xor(sum, 16, 64);
        sum += __shfl_xor(sum, 32, 64);
        const float rinv = 1.0f / sum;
#pragma unroll
        for (int nt = 0; nt < 9; ++nt) {
            bf16x4 pw;
#pragma unroll
            for (int j = 0; j < 4; ++j) pw[j] = (bf16_t)(s[nt][j] * rinv);
            *(bf16x4*)&pb[lrow * 168 + nt * 16 + lgrp * 4] = pw;
        }
        {
            uint2 z2 = make_uint2(0u, 0u);
            *(uint2*)&pb[lrow * 168 + 144 + lgrp * 4] = z2;
        }
        bf16x8 pa[5];
#pragma unroll
        for (int ks = 0; ks < 5; ++ks)
            pa[ks] = *(const bf16x8*)&pb[lrow * 168 + ks * 32 + lgrp * 8];
#pragma unroll
        for (int ks = 0; ks < 5; ++ks) PIN(pa[ks]);
        f32x4 o0{0.f, 0.f, 0.f, 0.f}, o1{0.f, 0.f, 0.f, 0.f};
#pragma unroll
        for (int ks = 0; ks < 5; ++ks) {
            o0 = __builtin_amdgcn_mfma_f32_16x16x32_bf16(pa[ks], va0[ks], o0, 0, 0, 0);
            o1 = __builtin_amdgcn_mfma_f32_16x16x32_bf16(pa[ks], va1[ks], o1, 0, 0, 0);
        }
#pragma unroll
        for (int j = 0; j < 4; ++j) {
            pb[(lgrp * 4 + j) * 168 + lrow]      = (bf16_t)o0[j];
            pb[(lgrp * 4 + j) * 168 + 16 + lrow] = (bf16_t)o1[j];
        }
        bf16x8 ov = *(const bf16x8*)&pb[lrow * 168 + lgrp * 8];
        *(bf16x8*)(ogp + (size_t)(t * 16 + lrow) * 192) = ov;
        qa = qa_n;
    }
}

// ======================= kernel 3: out-projection GEMM (rotated) ============
__global__ __launch_bounds__(256, 4)
void out_proj(const bf16_t* __restrict__ Og, const bf16_t* __restrict__ woutS,
              const float* __restrict__ b_out, float* __restrict__ out)
{
    __shared__ __align__(16) bf16_t Wb[2][6144];
    const int tid  = threadIdx.x;
    const int lane = tid & 63;
    const int wave = tid >> 6;
    const int lrow = lane & 15;
    const int lgrp = lane >> 4;
    const size_t row0 = (size_t)blockIdx.x * 64 + wave * 16;
    const int c0   = blockIdx.x % 6;                   // chunk rotation

    stage_chunk(&Wb[0][0], woutS + c0 * 6144, tid);

    bf16x8 af[6];
#pragma unroll
    for (int ks = 0; ks < 6; ++ks)
        af[ks] = *(const bf16x8*)(Og + (row0 + lrow) * 192 + ks * 32 + lgrp * 8);
    __syncthreads();

#pragma unroll 1
    for (int i = 0; i < 6; ++i) {
        int c = c0 + i; if (c >= 6) c -= 6;
        if (i < 5) {
            int nc = c + 1; if (nc >= 6) nc -= 6;
            stage_chunk(&Wb[(i + 1) & 1][0], woutS + nc * 6144, tid);
        }
        const bf16_t* wb = &Wb[i & 1][0];
        float b0 = b_out[c * 32 + lrow], b1 = b_out[c * 32 + 16 + lrow];
        f32x4 a0{b0, b0, b0, b0}, a1{b1, b1, b1, b1};
#pragma unroll
        for (int ks = 0; ks < 6; ++ks) {
            bf16x8 wf0 = *(const bf16x8*)&wb[swz_elem(lrow,      ks * 32 + lgrp * 8)];
            bf16x8 wf1 = *(const bf16x8*)&wb[swz_elem(16 + lrow, ks * 32 + lgrp * 8)];
            a0 = __builtin_amdgcn_mfma_f32_16x16x32_bf16(af[ks], wf0, a0, 0, 0, 0);
            a1 = __builtin_amdgcn_mfma_f32_16x16x32_bf16(af[ks], wf1, a1, 0, 0, 0);
        }
        __syncthreads();
#pragma unroll
        for (int j = 0; j < 4; ++j) {
            out[(row0 + lgrp * 4 + j) * 192 + c * 32 + lrow]      = a0[j];
            out[(row0 + lgrp * 4 + j) * 192 + c * 32 + 16 + lrow] = a1[j];
        }
    }
}

// ======================= launch =============================================
extern "C" void kernel_launch(void* const* d_in, const int* in_sizes, int n_in,
                              void* d_out, int out_size, void* d_ws, size_t ws_size,
                              hipStream_t stream) {
    const float* x     = (const float*)d_in[0];
    const float* mask  = (const float*)d_in[1];
    const float* w_qkv = (const float*)d_in[2];
    const float* b_qkv = (const float*)d_in[3];
    const float* bias  = (const float*)d_in[4];
    const float* w_out = (const float*)d_in[5];
    const float* b_out = (const float*)d_in[6];

    bf16_t* wqkvS = (bf16_t*)d_ws;                     //    110,592 elems
    bf16_t* woutS = wqkvS + 576 * 192;                 //     36,864
    bf16_t* Qg    = woutS + 192 * 192;                 // 27,426,816
    bf16_t* Kg    = Qg + (size_t)992 * 6 * 144 * 32;   // 27,426,816
    bf16_t* Vt    = Kg + (size_t)992 * 6 * 144 * 32;   // 30,474,240
    bf16_t* Og    = Vt + (size_t)992 * 6 * 32 * 160;   // 27,426,816
    bf16_t* biasP = Og + (size_t)992 * 144 * 192;      // 17,141,760
    bf16_t* maskP = biasP + (size_t)6696 * 2560;       // 22,855,680

    const size_t need_v10 = ((size_t)112902144 + 17141760 + 22855680) * 2;   // ~306 MB

    prep_weights<<<dim3(432), dim3(256), 0, stream>>>(w_qkv, w_out, wqkvS, woutS);
    qkv_gemm<<<dim3(1116), dim3(256), 0, stream>>>(x, b_qkv, wqkvS, Qg, Kg, Vt);

    if (ws_size >= need_v10) {
        prep_bm2<<<dim3(15624), dim3(256), 0, stream>>>(bias, mask, biasP, maskP);
        earth_attn_v10<<<dim3(5952), dim3(192), 0, stream>>>(Qg, Kg, Vt, maskP, biasP, Og);
    } else {
        earth_attn_v7<<<dim3(1488), dim3(256), 0, stream>>>(Qg, Kg, Vt, mask, bias, Og);
    }
    out_proj<<<dim3(2232), dim3(256), 0, stream>>>(Og, woutS, b_out, (float*)d_out);
}